// Round 2
// baseline (2070.923 us; speedup 1.0000x reference)
//
#include <hip/hip_runtime.h>
#include <stdint.h>

#define T_STEPS 512
#define BATCH   256
#define INP     128
#define HID     512
#define BGN     16   // batch groups (16 rows each)
#define CGN     8    // column groups (64 cols each)
#define RB      16   // rows per block
#define CB      64   // h-cols per block (16 per wave, both matrices per wave)
#define ZP      648  // LDS z row pitch in u16 (640 + 8 pad)

typedef float f32x4 __attribute__((ext_vector_type(4)));
typedef short s16x8 __attribute__((ext_vector_type(8)));
typedef unsigned short u16;
typedef unsigned int   u32;
typedef unsigned long long u64;

__device__ __forceinline__ u32 f2bf(float f) {
  union { float f; u32 u; } v; v.f = f;
  return (v.u + 0x7fffu + ((v.u >> 16) & 1u)) >> 16;  // RNE, bits in low 16
}

// d_ws: hb[4][BATCH][HID] bf16 ring (1 MB), memset 0xFF (poison = bf16 -NaN,
// unreachable: |h| < 1.01 by the bounded ODE dynamics).
//
// Flag-free sentinel protocol:
//   step t reads buffer t&3 (spin until non-poison), writes h(t+1) into
//   buffer (t+1)&3, and re-poisons its OWN 64-col slice of buffer (t+2)&3.
//   The vmcnt(0) before the h stores orders poison < h-data at the MALL;
//   a consumer's step-(t+2) poll is issued only after it observed h(t+1),
//   so it sees poison-or-newer — never stale h(t-2). Overwrite safety:
//   readers of a buffer finish a full step before its producer rewrites it
//   (4-deep ring). All traffic uses AGENT-scope relaxed atomics (the
//   cross-XCD-proven path); no flags, no fences, no inline-asm cache ops.

__global__ __launch_bounds__(256, 1)
void liquid_persistent(const float* __restrict__ x_seq,
                       const float* __restrict__ Wc, const float* __restrict__ bc,
                       const float* __restrict__ Wt, const float* __restrict__ bt,
                       const float* __restrict__ Wo, const float* __restrict__ bo,
                       float* __restrict__ y_out, float* __restrict__ tau_out,
                       u16* __restrict__ hb)
{
  const int tid  = threadIdx.x;
  const int l    = tid & 63;
  const int w    = tid >> 6;          // wave 0..3
  const int quad = l >> 4;
  const int ln   = l & 15;
  const int bg   = blockIdx.x & (BGN - 1);
  const int cg   = blockIdx.x >> 4;   // 0..7
  const int R0   = bg * RB;
  const int C0   = cg * CB;
  const int cn   = C0 + w * 16 + ln;  // this lane's output column (both matrices)

  __shared__ u16 zS[RB][ZP];          // [x(128) ; h(512)] bf16 per row

  // ---- register-resident weights: BOTH matrices for this wave's 16 cols ----
  s16x8 wfC[20], wfT[20];
#pragma unroll
  for (int kt = 0; kt < 20; ++kt) {
#pragma unroll
    for (int j = 0; j < 8; ++j) {
      int k = kt * 32 + quad * 8 + j;
      wfC[kt][j] = (short)f2bf(Wc[k * HID + cn]);
      wfT[kt][j] = (short)f2bf(Wt[k * HID + cn]);
    }
  }

  const float bcv = bc[cn], btv = bt[cn], wov = Wo[cn];
  const float boadd = (cg == 0 && w == 0) ? bo[0] : 0.0f;
  float hm[4] = {0.f, 0.f, 0.f, 0.f};

  const int xrow = tid >> 4;   // staging row 0..15
  const int xseg = tid & 15;

  // peer column-group indices (skip own)
  int ii[7];
#pragma unroll
  for (int jx = 0; jx < 7; ++jx) ii[jx] = jx + (jx >= cg ? 1 : 0);

  const size_t rowq = HID / 4;                  // u64 per h row
  u64* hbase = (u64*)(void*)hb;
  const size_t myrow = (size_t)(R0 + xrow) * rowq;

  // ---- pre-stage x(0) into zS.x ----
  {
    const float* xp = x_seq + ((size_t)0 * BATCH + R0 + xrow) * INP + xseg * 8;
    float4 a = *(const float4*)xp;
    float4 b = *(const float4*)(xp + 4);
    u64 w0 = (u64)f2bf(a.x) | ((u64)f2bf(a.y) << 16) |
             ((u64)f2bf(a.z) << 32) | ((u64)f2bf(a.w) << 48);
    u64 w1 = (u64)f2bf(b.x) | ((u64)f2bf(b.y) << 16) |
             ((u64)f2bf(b.z) << 32) | ((u64)f2bf(b.w) << 48);
    *(u64*)&zS[xrow][xseg * 8]     = w0;
    *(u64*)&zS[xrow][xseg * 8 + 4] = w1;
  }
  __syncthreads();

  for (int t = 0; t < T_STEPS; ++t) {
    // per-thread poll addresses in buffer t&3 (7 peer slices)
    const u64* rbase = hbase + (size_t)(t & 3) * BATCH * rowq + myrow + xseg;

    // ---- issue first sweep BEFORE Phase A (x-MFMAs hide the round trip) ----
    u64 tmp[7];
    if (t > 0) {
#pragma unroll
      for (int jx = 0; jx < 7; ++jx)
        tmp[jx] = __hip_atomic_load(rbase + ii[jx] * 16, __ATOMIC_RELAXED,
                                    __HIP_MEMORY_SCOPE_AGENT);
    }

    // ---- Phase A: x-part MFMAs (independent of h exchange) ----
    f32x4 aC0 = {0.f,0.f,0.f,0.f}, aC1 = {0.f,0.f,0.f,0.f};
    f32x4 aT0 = {0.f,0.f,0.f,0.f}, aT1 = {0.f,0.f,0.f,0.f};
    const u16* zb = &zS[ln][quad * 8];   // A layout: m=lane&15, k=quad*8+j
    {
      s16x8 a0 = *(const s16x8*)(zb);
      s16x8 a1 = *(const s16x8*)(zb + 32);
      s16x8 a2 = *(const s16x8*)(zb + 64);
      s16x8 a3 = *(const s16x8*)(zb + 96);
      aC0 = __builtin_amdgcn_mfma_f32_16x16x32_bf16(a0, wfC[0], aC0, 0,0,0);
      aT0 = __builtin_amdgcn_mfma_f32_16x16x32_bf16(a0, wfT[0], aT0, 0,0,0);
      aC1 = __builtin_amdgcn_mfma_f32_16x16x32_bf16(a1, wfC[1], aC1, 0,0,0);
      aT1 = __builtin_amdgcn_mfma_f32_16x16x32_bf16(a1, wfT[1], aT1, 0,0,0);
      aC0 = __builtin_amdgcn_mfma_f32_16x16x32_bf16(a2, wfC[2], aC0, 0,0,0);
      aT0 = __builtin_amdgcn_mfma_f32_16x16x32_bf16(a2, wfT[2], aT0, 0,0,0);
      aC1 = __builtin_amdgcn_mfma_f32_16x16x32_bf16(a3, wfC[3], aC1, 0,0,0);
      aT1 = __builtin_amdgcn_mfma_f32_16x16x32_bf16(a3, wfT[3], aT1, 0,0,0);
    }

    // ---- resolve poll: data valid iff neither dword is poison ----
    u64 hv[7];
    if (t == 0) {
#pragma unroll
      for (int jx = 0; jx < 7; ++jx) hv[jx] = 0;   // h(0) = 0
    } else {
      bool need[7];
      int pending = 0;
#pragma unroll
      for (int jx = 0; jx < 7; ++jx) {
        u64 v = tmp[jx];
        bool ok = ((u32)v != 0xFFFFFFFFu) && ((u32)(v >> 32) != 0xFFFFFFFFu);
        hv[jx] = v;
        need[jx] = !ok;
        pending += ok ? 0 : 1;
      }
      while (pending) {
#pragma unroll
        for (int jx = 0; jx < 7; ++jx)
          if (need[jx])
            tmp[jx] = __hip_atomic_load(rbase + ii[jx] * 16, __ATOMIC_RELAXED,
                                        __HIP_MEMORY_SCOPE_AGENT);
#pragma unroll
        for (int jx = 0; jx < 7; ++jx)
          if (need[jx]) {
            u64 v = tmp[jx];
            if (((u32)v != 0xFFFFFFFFu) && ((u32)(v >> 32) != 0xFFFFFFFFu)) {
              hv[jx] = v;
              need[jx] = false;
              --pending;
            }
          }
      }
    }

    // ---- re-poison own slice of buffer (t+2)&3 (ordered by vmcnt below) ----
    {
      u64* pp = hbase + (size_t)((t + 2) & 3) * BATCH * rowq + myrow
              + (C0 / 4 + xseg);
      __hip_atomic_store(pp, ~0ull, __ATOMIC_RELAXED, __HIP_MEMORY_SCOPE_AGENT);
    }

    // ---- x(t+1) prefetch (consumed at staging, after Phase C) ----
    const int tn = (t + 1 < T_STEPS) ? t + 1 : t;
    const float* xp = x_seq + ((size_t)tn * BATCH + R0 + xrow) * INP + xseg * 8;
    float4 xr0 = *(const float4*)xp;
    float4 xr1 = *(const float4*)(xp + 4);

    // ---- stage h into zS: 7 remote slices + own slice from registers ----
#pragma unroll
    for (int jx = 0; jx < 7; ++jx)
      *(u64*)&zS[xrow][INP + (ii[jx] * 16 + xseg) * 4] = hv[jx];
#pragma unroll
    for (int r = 0; r < 4; ++r)
      zS[quad * 4 + r][INP + cn] = (u16)f2bf(hm[r]);

    __syncthreads();   // barrier2: zS.h complete before Phase C

    // ---- Phase C: h-part MFMAs (4 independent accumulator chains) ----
#pragma unroll
    for (int kt = 4; kt < 20; kt += 2) {
      s16x8 a0 = *(const s16x8*)(zb + kt * 32);
      s16x8 a1 = *(const s16x8*)(zb + kt * 32 + 32);
      aC0 = __builtin_amdgcn_mfma_f32_16x16x32_bf16(a0, wfC[kt],   aC0, 0,0,0);
      aT0 = __builtin_amdgcn_mfma_f32_16x16x32_bf16(a0, wfT[kt],   aT0, 0,0,0);
      aC1 = __builtin_amdgcn_mfma_f32_16x16x32_bf16(a1, wfC[kt+1], aC1, 0,0,0);
      aT1 = __builtin_amdgcn_mfma_f32_16x16x32_bf16(a1, wfT[kt+1], aT1, 0,0,0);
    }
    aC0 += aC1;
    aT0 += aT1;

    // ---- stage x(t+1) into zS.x (all waves past Phase A via barrier2) ----
    {
      u64 w0 = (u64)f2bf(xr0.x) | ((u64)f2bf(xr0.y) << 16) |
               ((u64)f2bf(xr0.z) << 32) | ((u64)f2bf(xr0.w) << 48);
      u64 w1 = (u64)f2bf(xr1.x) | ((u64)f2bf(xr1.y) << 16) |
               ((u64)f2bf(xr1.z) << 32) | ((u64)f2bf(xr1.w) << 48);
      *(u64*)&zS[xrow][xseg * 8]     = w0;
      *(u64*)&zS[xrow][xseg * 8 + 4] = w1;
    }

    // ---- Phase D: epilogue (C-layout: col=ln, row=quad*4+r) ----
    float tauv[4];
#pragma unroll
    for (int r = 0; r < 4; ++r) {
      float pc = aC0[r] + bcv;
      float pt = aT0[r] + btv;
      pc = fminf(fmaxf(pc, -20.f), 20.f);
      float e  = __expf(2.f * pc);
      float cand = (e - 1.f) / (e + 1.f);          // tanh
      float tau  = 0.2f + 1.8f / (1.f + __expf(-pt));
      hm[r] += 0.1f * (cand - hm[r]) / tau;
      tauv[r] = tau;
    }

    // drain: orders the poison store before this step's h stores at the MALL
    // (x loads already consumed at staging -> this wait is nearly free)
    asm volatile("s_waitcnt vmcnt(0)" ::: "memory");

    // ---- h store: pack 4 cols into one u64, lanes ln%4==0 store ----
#pragma unroll
    for (int r = 0; r < 4; ++r) {
      u32 bits = f2bf(hm[r]);
      u32 b0   = bits | ((u32)__shfl_xor((int)bits, 1) << 16); // cols cn,cn+1
      u64 q    = (u64)b0 | ((u64)(u32)__shfl_xor((int)b0, 2) << 32);
      if (!(ln & 3)) {
        u64* hp = hbase + (size_t)((t + 1) & 3) * BATCH * rowq
                + (size_t)(R0 + quad * 4 + r) * rowq + (cn / 4);
        __hip_atomic_store(hp, q, __ATOMIC_RELAXED, __HIP_MEMORY_SCOPE_AGENT);
      }
    }

    __syncthreads();   // barrier3: zS.x staged before next Phase A

    // ---- tail (off the sync critical path): tau + y ----
#pragma unroll
    for (int r = 0; r < 4; ++r)
      __builtin_nontemporal_store(
          tauv[r],
          &tau_out[((size_t)t * BATCH + R0 + quad * 4 + r) * HID + cn]);
#pragma unroll
    for (int r = 0; r < 4; ++r) {
      float py = hm[r] * wov;
      py += __shfl_down(py, 8, 16);
      py += __shfl_down(py, 4, 16);
      py += __shfl_down(py, 2, 16);
      py += __shfl_down(py, 1, 16);
      if (ln == 0)
        atomicAdd(&y_out[t * BATCH + R0 + quad * 4 + r], py + boadd);
    }
  }
}

extern "C" void kernel_launch(void* const* d_in, const int* in_sizes, int n_in,
                              void* d_out, int out_size, void* d_ws, size_t ws_size,
                              hipStream_t stream) {
  (void)in_sizes; (void)n_in; (void)out_size; (void)ws_size;
  const float* x_seq = (const float*)d_in[0];
  const float* Wc    = (const float*)d_in[1];
  const float* bc    = (const float*)d_in[2];
  const float* Wt    = (const float*)d_in[3];
  const float* bt    = (const float*)d_in[4];
  const float* Wo    = (const float*)d_in[5];
  const float* bo    = (const float*)d_in[6];

  float* y_out   = (float*)d_out;                              // [T*B]
  float* tau_out = (float*)d_out + (size_t)T_STEPS * BATCH;    // [T*B*H]

  const size_t HB_BYTES = (size_t)4 * BATCH * HID * sizeof(u16); // 1 MB ring
  u16* hb = (u16*)d_ws;

  hipMemsetAsync(d_out, 0, (size_t)T_STEPS * BATCH * sizeof(float), stream);
  hipMemsetAsync(d_ws, 0xFF, HB_BYTES, stream);  // poison the whole ring

  liquid_persistent<<<dim3(BGN * CGN), dim3(256), 0, stream>>>(
      x_seq, Wc, bc, Wt, bt, Wo, bo, y_out, tau_out, hb);
}

// Round 3
// 1960.580 us; speedup vs baseline: 1.0563x; 1.0563x over previous
//
#include <hip/hip_runtime.h>
#include <stdint.h>

#define T_STEPS 512
#define BATCH   256
#define INP     128
#define HID     512
#define BGN     16   // batch groups (16 rows each)
#define CGN     8    // column groups (64 cols each)
#define RB      16   // rows per block
#define CB      64   // h-cols per block (16 per wave, both matrices per wave)
#define ZP      648  // LDS z row pitch in u16 (640 + 8 pad)

typedef float f32x4 __attribute__((ext_vector_type(4)));
typedef short s16x8 __attribute__((ext_vector_type(8)));
typedef unsigned short u16;
typedef unsigned int   u32;
typedef unsigned long long u64;

__device__ __forceinline__ u32 f2bf(float f) {
  union { float f; u32 u; } v; v.f = f;
  return (v.u + 0x7fffu + ((v.u >> 16) & 1u)) >> 16;  // RNE, bits in low 16
}

__device__ __forceinline__ float bf2f(u16 b) {
  union { u32 u; float f; } v; v.u = ((u32)b) << 16;
  return v.f;
}

// d_ws: hb[4][BATCH][HID] bf16 ring (1 MB), memset 0xFF (poison = bf16 -NaN,
// unreachable: |h| < 1.01 by the bounded ODE dynamics).
//
// Flag-free sentinel protocol (unchanged from r2, proven correct):
//   step t reads buffer t&3 (spin until non-poison), writes h(t+1) into
//   buffer (t+1)&3, re-poisons own slice of buffer (t+2)&3. vmcnt(0)
//   before the h stores orders poison < h-data at the MALL.
//
// NEW in r3: y-reduction is atomic-free. Block cg owns batch rows
// {2cg, 2cg+1} of its bg; at iteration t+1 the staged zS.h IS h(t+1), so
// y(t) is a local dot with Wo -> plain store. One extra gather iteration
// (t == T_STEPS) covers y(T-1). Removes 8192 same-line atomicAdds/step
// (256 per 64B line) whose completion sat inside the vmcnt(0) that gates
// the h-store -- the suspected ring pace-setter.

__global__ __launch_bounds__(256, 1)
void liquid_persistent(const float* __restrict__ x_seq,
                       const float* __restrict__ Wc, const float* __restrict__ bc,
                       const float* __restrict__ Wt, const float* __restrict__ bt,
                       const float* __restrict__ Wo, const float* __restrict__ bo,
                       float* __restrict__ y_out, float* __restrict__ tau_out,
                       u16* __restrict__ hb)
{
  const int tid  = threadIdx.x;
  const int l    = tid & 63;
  const int w    = tid >> 6;          // wave 0..3
  const int quad = l >> 4;
  const int ln   = l & 15;
  const int bg   = blockIdx.x & (BGN - 1);
  const int cg   = blockIdx.x >> 4;   // 0..7
  const int R0   = bg * RB;
  const int C0   = cg * CB;
  const int cn   = C0 + w * 16 + ln;  // this lane's output column (both matrices)

  __shared__ u16 zS[RB][ZP];          // [x(128) ; h(512)] bf16 per row
  __shared__ float ypS[4];            // y partials (one per wave)

  // ---- register-resident weights: BOTH matrices for this wave's 16 cols ----
  s16x8 wfC[20], wfT[20];
#pragma unroll
  for (int kt = 0; kt < 20; ++kt) {
#pragma unroll
    for (int j = 0; j < 8; ++j) {
      int k = kt * 32 + quad * 8 + j;
      wfC[kt][j] = (short)f2bf(Wc[k * HID + cn]);
      wfT[kt][j] = (short)f2bf(Wt[k * HID + cn]);
    }
  }

  const float bcv = bc[cn], btv = bt[cn];
  const float bov = bo[0];
  float hm[4] = {0.f, 0.f, 0.f, 0.f};

  const int xrow = tid >> 4;   // staging row 0..15
  const int xseg = tid & 15;

  // y-compute mapping: waves {0,1} -> local row 2cg, waves {2,3} -> 2cg+1;
  // within a row, wave parity selects col half; lane covers 4 cols.
  const int yrow = 2 * cg + (w >> 1);
  const int yc0  = (w & 1) * 256 + l * 4;
  const float4 wo4 = *(const float4*)&Wo[yc0];

  // peer column-group indices (skip own)
  int ii[7];
#pragma unroll
  for (int jx = 0; jx < 7; ++jx) ii[jx] = jx + (jx >= cg ? 1 : 0);

  const size_t rowq = HID / 4;                  // u64 per h row
  u64* hbase = (u64*)(void*)hb;
  const size_t myrow = (size_t)(R0 + xrow) * rowq;

  // ---- pre-stage x(0) into zS.x ----
  {
    const float* xp = x_seq + ((size_t)0 * BATCH + R0 + xrow) * INP + xseg * 8;
    float4 a = *(const float4*)xp;
    float4 b = *(const float4*)(xp + 4);
    u64 w0 = (u64)f2bf(a.x) | ((u64)f2bf(a.y) << 16) |
             ((u64)f2bf(a.z) << 32) | ((u64)f2bf(a.w) << 48);
    u64 w1 = (u64)f2bf(b.x) | ((u64)f2bf(b.y) << 16) |
             ((u64)f2bf(b.z) << 32) | ((u64)f2bf(b.w) << 48);
    *(u64*)&zS[xrow][xseg * 8]     = w0;
    *(u64*)&zS[xrow][xseg * 8 + 4] = w1;
  }
  __syncthreads();

  for (int t = 0; t <= T_STEPS; ++t) {
    // per-thread poll addresses in buffer t&3 (7 peer slices)
    const u64* rbase = hbase + (size_t)(t & 3) * BATCH * rowq + myrow + xseg;

    // ---- issue first sweep BEFORE Phase A (x-MFMAs hide the round trip) ----
    u64 tmp[7];
    if (t > 0) {
#pragma unroll
      for (int jx = 0; jx < 7; ++jx)
        tmp[jx] = __hip_atomic_load(rbase + ii[jx] * 16, __ATOMIC_RELAXED,
                                    __HIP_MEMORY_SCOPE_AGENT);
    }

    // ---- Phase A: x-part MFMAs (independent of h exchange) ----
    f32x4 aC0 = {0.f,0.f,0.f,0.f}, aC1 = {0.f,0.f,0.f,0.f};
    f32x4 aT0 = {0.f,0.f,0.f,0.f}, aT1 = {0.f,0.f,0.f,0.f};
    const u16* zb = &zS[ln][quad * 8];   // A layout: m=lane&15, k=quad*8+j
    if (t < T_STEPS) {
      s16x8 a0 = *(const s16x8*)(zb);
      s16x8 a1 = *(const s16x8*)(zb + 32);
      s16x8 a2 = *(const s16x8*)(zb + 64);
      s16x8 a3 = *(const s16x8*)(zb + 96);
      aC0 = __builtin_amdgcn_mfma_f32_16x16x32_bf16(a0, wfC[0], aC0, 0,0,0);
      aT0 = __builtin_amdgcn_mfma_f32_16x16x32_bf16(a0, wfT[0], aT0, 0,0,0);
      aC1 = __builtin_amdgcn_mfma_f32_16x16x32_bf16(a1, wfC[1], aC1, 0,0,0);
      aT1 = __builtin_amdgcn_mfma_f32_16x16x32_bf16(a1, wfT[1], aT1, 0,0,0);
      aC0 = __builtin_amdgcn_mfma_f32_16x16x32_bf16(a2, wfC[2], aC0, 0,0,0);
      aT0 = __builtin_amdgcn_mfma_f32_16x16x32_bf16(a2, wfT[2], aT0, 0,0,0);
      aC1 = __builtin_amdgcn_mfma_f32_16x16x32_bf16(a3, wfC[3], aC1, 0,0,0);
      aT1 = __builtin_amdgcn_mfma_f32_16x16x32_bf16(a3, wfT[3], aT1, 0,0,0);
    }

    // ---- resolve poll: data valid iff neither dword is poison ----
    u64 hv[7];
    if (t == 0) {
#pragma unroll
      for (int jx = 0; jx < 7; ++jx) hv[jx] = 0;   // h(0) = 0
    } else {
      bool need[7];
      int pending = 0;
#pragma unroll
      for (int jx = 0; jx < 7; ++jx) {
        u64 v = tmp[jx];
        bool ok = ((u32)v != 0xFFFFFFFFu) && ((u32)(v >> 32) != 0xFFFFFFFFu);
        hv[jx] = v;
        need[jx] = !ok;
        pending += ok ? 0 : 1;
      }
      while (pending) {
#pragma unroll
        for (int jx = 0; jx < 7; ++jx)
          if (need[jx])
            tmp[jx] = __hip_atomic_load(rbase + ii[jx] * 16, __ATOMIC_RELAXED,
                                        __HIP_MEMORY_SCOPE_AGENT);
#pragma unroll
        for (int jx = 0; jx < 7; ++jx)
          if (need[jx]) {
            u64 v = tmp[jx];
            if (((u32)v != 0xFFFFFFFFu) && ((u32)(v >> 32) != 0xFFFFFFFFu)) {
              hv[jx] = v;
              need[jx] = false;
              --pending;
            }
          }
      }
    }

    // ---- re-poison own slice of buffer (t+2)&3 (ordered by vmcnt below) ----
    if (t < T_STEPS) {
      u64* pp = hbase + (size_t)((t + 2) & 3) * BATCH * rowq + myrow
              + (C0 / 4 + xseg);
      __hip_atomic_store(pp, ~0ull, __ATOMIC_RELAXED, __HIP_MEMORY_SCOPE_AGENT);
    }

    // ---- x(t+1) prefetch (consumed at staging, after Phase C) ----
    float4 xr0, xr1;
    if (t < T_STEPS) {
      const int tn = (t + 1 < T_STEPS) ? t + 1 : t;
      const float* xp = x_seq + ((size_t)tn * BATCH + R0 + xrow) * INP + xseg * 8;
      xr0 = *(const float4*)xp;
      xr1 = *(const float4*)(xp + 4);
    }

    // ---- stage h into zS: 7 remote slices + own slice from registers ----
#pragma unroll
    for (int jx = 0; jx < 7; ++jx)
      *(u64*)&zS[xrow][INP + (ii[jx] * 16 + xseg) * 4] = hv[jx];
#pragma unroll
    for (int r = 0; r < 4; ++r)
      zS[quad * 4 + r][INP + cn] = (u16)f2bf(hm[r]);

    __syncthreads();   // barrier2: zS.h complete before Phase C / y-compute

    float tauv[4];
    if (t < T_STEPS) {
      // ---- Phase C: h-part MFMAs (4 independent accumulator chains) ----
#pragma unroll
      for (int kt = 4; kt < 20; kt += 2) {
        s16x8 a0 = *(const s16x8*)(zb + kt * 32);
        s16x8 a1 = *(const s16x8*)(zb + kt * 32 + 32);
        aC0 = __builtin_amdgcn_mfma_f32_16x16x32_bf16(a0, wfC[kt],   aC0, 0,0,0);
        aT0 = __builtin_amdgcn_mfma_f32_16x16x32_bf16(a0, wfT[kt],   aT0, 0,0,0);
        aC1 = __builtin_amdgcn_mfma_f32_16x16x32_bf16(a1, wfC[kt+1], aC1, 0,0,0);
        aT1 = __builtin_amdgcn_mfma_f32_16x16x32_bf16(a1, wfT[kt+1], aT1, 0,0,0);
      }
      aC0 += aC1;
      aT0 += aT1;

      // ---- stage x(t+1) into zS.x (all waves past Phase A via barrier2) ----
      u64 w0 = (u64)f2bf(xr0.x) | ((u64)f2bf(xr0.y) << 16) |
               ((u64)f2bf(xr0.z) << 32) | ((u64)f2bf(xr0.w) << 48);
      u64 w1 = (u64)f2bf(xr1.x) | ((u64)f2bf(xr1.y) << 16) |
               ((u64)f2bf(xr1.z) << 32) | ((u64)f2bf(xr1.w) << 48);
      *(u64*)&zS[xrow][xseg * 8]     = w0;
      *(u64*)&zS[xrow][xseg * 8 + 4] = w1;

      // ---- Phase D: epilogue (C-layout: col=ln, row=quad*4+r) ----
#pragma unroll
      for (int r = 0; r < 4; ++r) {
        float pc = aC0[r] + bcv;
        float pt = aT0[r] + btv;
        pc = fminf(fmaxf(pc, -20.f), 20.f);
        float e  = __expf(2.f * pc);
        float cand = (e - 1.f) / (e + 1.f);          // tanh
        float tau  = 0.2f + 1.8f / (1.f + __expf(-pt));
        hm[r] += 0.1f * (cand - hm[r]) / tau;
        tauv[r] = tau;
      }

      // drain: orders the poison store before this step's h stores at the MALL.
      // With y atomics gone, nothing slow is outstanding here.
      asm volatile("s_waitcnt vmcnt(0)" ::: "memory");

      // ---- h store: pack 4 cols into one u64, lanes ln%4==0 store ----
#pragma unroll
      for (int r = 0; r < 4; ++r) {
        u32 bits = f2bf(hm[r]);
        u32 b0   = bits | ((u32)__shfl_xor((int)bits, 1) << 16);
        u64 q    = (u64)b0 | ((u64)(u32)__shfl_xor((int)b0, 2) << 32);
        if (!(ln & 3)) {
          u64* hp = hbase + (size_t)((t + 1) & 3) * BATCH * rowq
                  + (size_t)(R0 + quad * 4 + r) * rowq + (cn / 4);
          __hip_atomic_store(hp, q, __ATOMIC_RELAXED, __HIP_MEMORY_SCOPE_AGENT);
        }
      }
    }

    // ---- y(t-1) partials from staged zS.h (atomic-free; off store path) ----
    if (t > 0) {
      u64 hq = *(const u64*)&zS[yrow][INP + yc0];
      float py = bf2f((u16)hq)          * wo4.x
               + bf2f((u16)(hq >> 16))  * wo4.y
               + bf2f((u16)(hq >> 32))  * wo4.z
               + bf2f((u16)(hq >> 48))  * wo4.w;
      py += __shfl_down(py, 32);
      py += __shfl_down(py, 16);
      py += __shfl_down(py, 8);
      py += __shfl_down(py, 4);
      py += __shfl_down(py, 2);
      py += __shfl_down(py, 1);
      if (l == 0) ypS[w] = py;
    }

    __syncthreads();   // barrier3: zS.x staged + ypS complete

    if (t > 0 && tid < 2) {
      float yv = ypS[tid * 2] + ypS[tid * 2 + 1] + bov;
      y_out[(size_t)(t - 1) * BATCH + R0 + 2 * cg + tid] = yv;
    }

    // ---- tau tail (off the sync critical path) ----
    if (t < T_STEPS) {
#pragma unroll
      for (int r = 0; r < 4; ++r)
        __builtin_nontemporal_store(
            tauv[r],
            &tau_out[((size_t)t * BATCH + R0 + quad * 4 + r) * HID + cn]);
    }
  }
}

extern "C" void kernel_launch(void* const* d_in, const int* in_sizes, int n_in,
                              void* d_out, int out_size, void* d_ws, size_t ws_size,
                              hipStream_t stream) {
  (void)in_sizes; (void)n_in; (void)out_size; (void)ws_size;
  const float* x_seq = (const float*)d_in[0];
  const float* Wc    = (const float*)d_in[1];
  const float* bc    = (const float*)d_in[2];
  const float* Wt    = (const float*)d_in[3];
  const float* bt    = (const float*)d_in[4];
  const float* Wo    = (const float*)d_in[5];
  const float* bo    = (const float*)d_in[6];

  float* y_out   = (float*)d_out;                              // [T*B]
  float* tau_out = (float*)d_out + (size_t)T_STEPS * BATCH;    // [T*B*H]

  const size_t HB_BYTES = (size_t)4 * BATCH * HID * sizeof(u16); // 1 MB ring
  u16* hb = (u16*)d_ws;

  hipMemsetAsync(d_ws, 0xFF, HB_BYTES, stream);  // poison the whole ring

  liquid_persistent<<<dim3(BGN * CGN), dim3(256), 0, stream>>>(
      x_seq, Wc, bc, Wt, bt, Wo, bo, y_out, tau_out, hb);
}